// Round 11
// baseline (132.471 us; speedup 1.0000x reference)
//
#include <hip/hip_runtime.h>
#include <hip/hip_bf16.h>
#include <math.h>

// Problem constants
#define Bc 4
#define Nc 1024
#define Ec 1024
#define Hc 16
#define Dc 64
#define Mc 4096                    // B*N rows
#define OUT0_ELEMS 4194304         // B*H*N*D
#define ATTN_ELEMS 67108864ULL     // B*H*N*N floats
#define SCRATCH_OFF 58720256       // float offset into attn region for bf16 scratch
#define NTK 32                     // K-tiles (BK=32) in proj

typedef __attribute__((ext_vector_type(4))) float f32x4;
typedef __attribute__((ext_vector_type(16))) float f32x16;
typedef __attribute__((ext_vector_type(8))) short s16x8;

// Hardware bf16 convert (compiler pairs into v_cvt_pk_bf16_f32)
__device__ __forceinline__ short f2bf(float f) {
    union { __bf16 h; short s; } c; c.h = (__bf16)f; return c.s;
}

// async global->LDS, 16B per lane; LDS dest = wave-uniform base + lane*16
typedef const __attribute__((address_space(1))) char gch;
typedef __attribute__((address_space(3))) char lch;
__device__ __forceinline__ void gload16(const short* g, short* l) {
    __builtin_amdgcn_global_load_lds((gch*)g, (lch*)l, 16, 0, 0);
}

// ---------------------------------------------------------------------------
// fp32 -> bf16 pre-pass (UNCHANGED).
// ---------------------------------------------------------------------------
__global__ __launch_bounds__(256)
void cvt_kernel(const float* __restrict__ xq, const float* __restrict__ xk,
                const float* __restrict__ xv, const float* __restrict__ wq,
                const float* __restrict__ wk, const float* __restrict__ wv,
                short* __restrict__ dst)
{
    const int which = blockIdx.y;
    const float* src; size_t n, off;
    switch (which) {
      case 0:  src = xq; n = 4194304; off = 0;        break;
      case 1:  src = xk; n = 4194304; off = 4194304;  break;
      case 2:  src = xv; n = 4194304; off = 8388608;  break;
      case 3:  src = wq; n = 1048576; off = 12582912; break;
      case 4:  src = wk; n = 1048576; off = 13631488; break;
      default: src = wv; n = 1048576; off = 14680064; break;
    }
    const size_t i = ((size_t)blockIdx.x * 256 + threadIdx.x) * 8;
    if (i >= n) return;
    f32x4 a = *(const f32x4*)(src + i);
    f32x4 b = *(const f32x4*)(src + i + 4);
    s16x8 o;
    o[0] = f2bf(a[0]); o[1] = f2bf(a[1]); o[2] = f2bf(a[2]); o[3] = f2bf(a[3]);
    o[4] = f2bf(b[0]); o[5] = f2bf(b[1]); o[6] = f2bf(b[2]); o[7] = f2bf(b[3]);
    *(s16x8*)(dst + off + i) = o;
}

// ---------------------------------------------------------------------------
// Projection GEMM (UNCHANGED round-7 config: 3-buffer counted-vmcnt
// pipeline, 64x64/wave, 128x128 block, source-side XOR swizzle).
// ---------------------------------------------------------------------------
__global__ __launch_bounds__(256)
void proj_kernel(const short* __restrict__ xall, const short* __restrict__ wall,
                 const float* __restrict__ bq, const float* __restrict__ bk,
                 const float* __restrict__ bv,
                 short* __restrict__ qws, short* __restrict__ kws,
                 float* __restrict__ vout)
{
    const int sel = blockIdx.z;
    const short* X = xall + (size_t)sel * 4194304;
    const short* W = wall + (size_t)sel * 1048576;
    const float* bias = (sel == 0) ? bq : (sel == 1) ? bk : bv;

    __shared__ __align__(16) short lA[3][128 * 32];
    __shared__ __align__(16) short lB[3][128 * 32];

    const int t    = threadIdx.x;
    const int lane = t & 63;
    const int w    = t >> 6;
    const int wr   = w >> 1, wc = w & 1;      // 2x2 wave grid, 64x64 each
    const int li   = lane & 15, g = lane >> 4;
    const int bm   = blockIdx.x * 128;
    const int bn   = blockIdx.y * 128;

    const int sr = lane >> 2;                 // 0..15
    const int c_ = lane & 3;                  // 16B chunk within 64B row

    f32x4 acc[4][4];
#pragma unroll
    for (int i = 0; i < 4; ++i)
#pragma unroll
        for (int j = 0; j < 4; ++j)
            acc[i][j] = (f32x4){0.f, 0.f, 0.f, 0.f};

#define STAGE(buf, kt)                                                        \
    {                                                                         \
        const int kb = (kt) * 32;                                             \
        _Pragma("unroll")                                                     \
        for (int j = 0; j < 2; ++j) {                                         \
            const int row = w * 32 + j * 16 + sr;                             \
            const int cg  = (c_ ^ ((row >> 1) & 3)) * 8;                      \
            gload16(X + (size_t)(bm + row) * Ec + kb + cg,                    \
                    &lA[buf][(w * 32 + j * 16) * 32]);                        \
            gload16(W + (size_t)(bn + row) * Ec + kb + cg,                    \
                    &lB[buf][(w * 32 + j * 16) * 32]);                        \
        }                                                                     \
    }

    STAGE(0, 0);
    STAGE(1, 1);
    asm volatile("s_waitcnt vmcnt(4)" ::: "memory");   // tile 0 staged
    __builtin_amdgcn_s_barrier();

    for (int kt = 0; kt < NTK; ++kt) {
        const int cur = kt % 3;
        if (kt + 2 < NTK) STAGE((kt + 2) % 3, kt + 2);  // prefetch 2 ahead

        s16x8 aF[4], bF[4];
#pragma unroll
        for (int mt = 0; mt < 4; ++mt) {
            const int r = wr * 64 + mt * 16 + li;
            aF[mt] = *(const s16x8*)&lA[cur][r * 32 + ((g ^ ((r >> 1) & 3)) * 8)];
        }
#pragma unroll
        for (int nt = 0; nt < 4; ++nt) {
            const int r = wc * 64 + nt * 16 + li;
            bF[nt] = *(const s16x8*)&lB[cur][r * 32 + ((g ^ ((r >> 1) & 3)) * 8)];
        }
#pragma unroll
        for (int mt = 0; mt < 4; ++mt)
#pragma unroll
            for (int nt = 0; nt < 4; ++nt)
                acc[mt][nt] = __builtin_amdgcn_mfma_f32_16x16x32_bf16(
                    aF[mt], bF[nt], acc[mt][nt], 0, 0, 0);

        if (kt + 2 < NTK) {
            asm volatile("s_waitcnt vmcnt(4)" ::: "memory");
        } else {
            asm volatile("s_waitcnt vmcnt(0)" ::: "memory");
        }
        __builtin_amdgcn_s_barrier();
    }
#undef STAGE

    short* dstBF = (sel == 0) ? qws : kws;
#pragma unroll
    for (int nt = 0; nt < 4; ++nt) {
        const int col = bn + wc * 64 + nt * 16 + li;
        const float bcol = bias[col];
        const int h = col >> 6, d = col & 63;
#pragma unroll
        for (int mt = 0; mt < 4; ++mt) {
#pragma unroll
            for (int r = 0; r < 4; ++r) {
                const int row = bm + wr * 64 + mt * 16 + g * 4 + r;
                const int bb = row >> 10, n = row & 1023;
                const size_t off = ((size_t)(bb * Hc + h) * Nc + n) * Dc + d;
                const float val = acc[mt][nt][r] + bcol;
                if (sel == 2)
                    vout[off] = val;
                else
                    dstBF[off] = f2bf(val);
            }
        }
    }
}

// ---------------------------------------------------------------------------
// Scores + softmax, round-11: identical to round 10 EXCEPT stores are plain
// (cached) instead of nontemporal — isolating the NT flag's effect on the
// HBM write path (NT was bundled with XCD clustering in round 5, never
// isolated; hypothesis: NT defeats L2 write-back batching -> poor HBM page
// locality across ~512 concurrent 4KB-strided streams).
// ---------------------------------------------------------------------------
__global__ __launch_bounds__(512, 4)
void attn_kernel(const short* __restrict__ qws, const short* __restrict__ kws,
                 float* __restrict__ attnOut)
{
    const int bid = blockIdx.x;                 // 0..2047
    const int rb  = (bid >> 3) & 31;            // 32-row block
    const int bh  = ((bid & 7) << 3) | (bid >> 8);  // head: bid%8 == bh>>3
    const int t  = threadIdx.x;
    const int w  = t >> 6;                      // 0..7
    const int lane = t & 63;
    const int li = lane & 31;
    const int hi = lane >> 5;

    const short* Qb = qws + (size_t)bh * (Nc * Dc);
    const short* Kb = kws + (size_t)bh * (Nc * Dc);

    // Q fragments: lane holds Q[rb*32+li][s*16 + hi*8 + i]
    s16x8 qF[4];
    {
        const short* qp = Qb + (size_t)(rb * 32 + li) * Dc + hi * 8;
#pragma unroll
        for (int s = 0; s < 4; ++s)
            qF[s] = *(const s16x8*)(qp + s * 16);
    }

    f32x16 acc[4];
#pragma unroll
    for (int i = 0; i < 4; ++i) acc[i] = (f32x16)(0.f);

    const int colbase = w * 128;                // wave owns 128 cols
#pragma unroll
    for (int ct = 0; ct < 4; ++ct) {
        const short* kp = Kb + (size_t)(colbase + ct * 32 + li) * Dc + hi * 8;
#pragma unroll
        for (int s = 0; s < 4; ++s) {
            s16x8 kf = *(const s16x8*)(kp + s * 16);
            acc[ct] = __builtin_amdgcn_mfma_f32_32x32x16_bf16(qF[s], kf, acc[ct], 0, 0, 0);
        }
    }

    // ---- exp + row partial sum (no max subtraction) ----
    const float c = 1.44269504f / 32.0f;   // log2(e)/SCALE, SCALE = 32
    float sm[16];
#pragma unroll
    for (int r = 0; r < 16; ++r) sm[r] = 0.f;
#pragma unroll
    for (int ct = 0; ct < 4; ++ct) {
#pragma unroll
        for (int r = 0; r < 16; ++r) {
            float p = __builtin_amdgcn_exp2f(acc[ct][r] * c);
            acc[ct][r] = p;
            sm[r] += p;
        }
    }
    // intra-wave (32-lane half) reduce
#pragma unroll
    for (int r = 0; r < 16; ++r) {
#pragma unroll
        for (int off = 1; off < 32; off <<= 1)
            sm[r] += __shfl_xor(sm[r], off);
    }

    __shared__ float red[8][32];
    if (li == 0) {
#pragma unroll
        for (int r = 0; r < 16; ++r)
            red[w][(r & 3) + 8 * (r >> 2) + 4 * hi] = sm[r];
    }
    __syncthreads();
#pragma unroll
    for (int r = 0; r < 16; ++r) {
        const int row = (r & 3) + 8 * (r >> 2) + 4 * hi;
        float s = red[0][row] + red[1][row] + red[2][row] + red[3][row] +
                  red[4][row] + red[5][row] + red[6][row] + red[7][row];
        sm[r] = 1.0f / s;
    }

    // ---- normalized stores: plain cached (A/B vs round-10's NT) ----
    float* outp = attnOut + (size_t)bh * (Nc * Nc) + (size_t)(rb * 32) * Nc;
#pragma unroll
    for (int ct = 0; ct < 4; ++ct) {
        const int col = colbase + ct * 32 + li;
#pragma unroll
        for (int r = 0; r < 16; ++r) {
            const int row = (r & 3) + 8 * (r >> 2) + 4 * hi;
            outp[(size_t)row * Nc + col] = acc[ct][r] * sm[r];
        }
    }
}

extern "C" void kernel_launch(void* const* d_in, const int* in_sizes, int n_in,
                              void* d_out, int out_size, void* d_ws, size_t ws_size,
                              hipStream_t stream) {
    const float* q  = (const float*)d_in[0];
    const float* k  = (const float*)d_in[1];
    const float* v  = (const float*)d_in[2];
    const float* Wq = (const float*)d_in[3];
    const float* bq = (const float*)d_in[4];
    const float* Wk = (const float*)d_in[5];
    const float* bk = (const float*)d_in[6];
    const float* Wv = (const float*)d_in[7];
    const float* bv = (const float*)d_in[8];

    float* out0 = (float*)d_out;                      // (B,H,N,D) fp32
    float* attn = (float*)d_out + OUT0_ELEMS;         // (B,H,N,N) fp32

    // bf16 scratch in the TAIL of the attn region: proj reads it, then
    // attn_kernel overwrites the whole region. 15M shorts = 30 MB.
    short* s16  = (short*)(attn + SCRATCH_OFF);
    short* xall = s16;                                // Xq|Xk|Xv bf16
    short* wall = s16 + 12582912;                     // Wq|Wk|Wv bf16

    short* qws = (short*)d_ws;                        // bf16 Q [b][h][n][d]
    short* kws = qws + (size_t)Mc * Ec;               // bf16 K [b][h][n][d]

    cvt_kernel<<<dim3(2048, 6), 256, 0, stream>>>(q, k, v, Wq, Wk, Wv, s16);
    proj_kernel<<<dim3(32, 8, 3), 256, 0, stream>>>(
        xall, wall, bq, bk, bv, qws, kws, out0);
    attn_kernel<<<2048, 512, 0, stream>>>(qws, kws, attn);
}

// Round 12
// 127.747 us; speedup vs baseline: 1.0370x; 1.0370x over previous
//
#include <hip/hip_runtime.h>
#include <hip/hip_bf16.h>
#include <math.h>

// Problem constants
#define Bc 4
#define Nc 1024
#define Ec 1024
#define Hc 16
#define Dc 64
#define Mc 4096                    // B*N rows
#define OUT0_ELEMS 4194304         // B*H*N*D
#define ATTN_ELEMS 67108864ULL     // B*H*N*N floats
#define SCRATCH_OFF 58720256       // float offset into attn region for bf16 scratch
#define NTK 32                     // K-tiles (BK=32) in proj

typedef __attribute__((ext_vector_type(4))) float f32x4;
typedef __attribute__((ext_vector_type(16))) float f32x16;
typedef __attribute__((ext_vector_type(8))) short s16x8;
typedef __attribute__((ext_vector_type(4))) short s16x4;

// Hardware bf16 convert (compiler pairs into v_cvt_pk_bf16_f32)
__device__ __forceinline__ short f2bf(float f) {
    union { __bf16 h; short s; } c; c.h = (__bf16)f; return c.s;
}
__device__ __forceinline__ s16x4 pk4(const f32x4 v) {
    s16x4 r;
    r[0] = f2bf(v[0]); r[1] = f2bf(v[1]); r[2] = f2bf(v[2]); r[3] = f2bf(v[3]);
    return r;
}

// async global->LDS, 16B per lane; LDS dest = wave-uniform base + lane*16
typedef const __attribute__((address_space(1))) char gch;
typedef __attribute__((address_space(3))) char lch;
__device__ __forceinline__ void gload16(const short* g, short* l) {
    __builtin_amdgcn_global_load_lds((gch*)g, (lch*)l, 16, 0, 0);
}

// ---------------------------------------------------------------------------
// fp32 -> bf16 pre-pass: Q/K inputs only (Xq, Xk, Wq, Wk).
// ---------------------------------------------------------------------------
__global__ __launch_bounds__(256)
void cvt_kernel(const float* __restrict__ xq, const float* __restrict__ xk,
                const float* __restrict__ wq, const float* __restrict__ wk,
                short* __restrict__ dst)
{
    const int which = blockIdx.y;
    const float* src; size_t n, off;
    switch (which) {
      case 0:  src = xq; n = 4194304; off = 0;       break;
      case 1:  src = xk; n = 4194304; off = 4194304; break;
      case 2:  src = wq; n = 1048576; off = 8388608; break;
      default: src = wk; n = 1048576; off = 9437184; break;
    }
    const size_t i = ((size_t)blockIdx.x * 256 + threadIdx.x) * 8;
    if (i >= n) return;
    f32x4 a = *(const f32x4*)(src + i);
    f32x4 b = *(const f32x4*)(src + i + 4);
    s16x8 o;
    o[0] = f2bf(a[0]); o[1] = f2bf(a[1]); o[2] = f2bf(a[2]); o[3] = f2bf(a[3]);
    o[4] = f2bf(b[0]); o[5] = f2bf(b[1]); o[6] = f2bf(b[2]); o[7] = f2bf(b[3]);
    *(s16x8*)(dst + off + i) = o;
}

// ---------------------------------------------------------------------------
// Q/K projection GEMM (round-7 structure, sel in {0,1} only).
// ---------------------------------------------------------------------------
__global__ __launch_bounds__(256)
void proj_kernel(const short* __restrict__ xall, const short* __restrict__ wall,
                 const float* __restrict__ bq, const float* __restrict__ bk,
                 short* __restrict__ qws, short* __restrict__ kws)
{
    const int sel = blockIdx.z;
    const short* X = xall + (size_t)sel * 4194304;
    const short* W = wall + (size_t)sel * 1048576;
    const float* bias = (sel == 0) ? bq : bk;

    __shared__ __align__(16) short lA[3][128 * 32];
    __shared__ __align__(16) short lB[3][128 * 32];

    const int t    = threadIdx.x;
    const int lane = t & 63;
    const int w    = t >> 6;
    const int wr   = w >> 1, wc = w & 1;      // 2x2 wave grid, 64x64 each
    const int li   = lane & 15, g = lane >> 4;
    const int bm   = blockIdx.x * 128;
    const int bn   = blockIdx.y * 128;

    const int sr = lane >> 2;                 // 0..15
    const int c_ = lane & 3;                  // 16B chunk within 64B row

    f32x4 acc[4][4];
#pragma unroll
    for (int i = 0; i < 4; ++i)
#pragma unroll
        for (int j = 0; j < 4; ++j)
            acc[i][j] = (f32x4){0.f, 0.f, 0.f, 0.f};

#define STAGE(buf, kt)                                                        \
    {                                                                         \
        const int kb = (kt) * 32;                                             \
        _Pragma("unroll")                                                     \
        for (int j = 0; j < 2; ++j) {                                         \
            const int row = w * 32 + j * 16 + sr;                             \
            const int cg  = (c_ ^ ((row >> 1) & 3)) * 8;                      \
            gload16(X + (size_t)(bm + row) * Ec + kb + cg,                    \
                    &lA[buf][(w * 32 + j * 16) * 32]);                        \
            gload16(W + (size_t)(bn + row) * Ec + kb + cg,                    \
                    &lB[buf][(w * 32 + j * 16) * 32]);                        \
        }                                                                     \
    }

    STAGE(0, 0);
    STAGE(1, 1);
    asm volatile("s_waitcnt vmcnt(4)" ::: "memory");   // tile 0 staged
    __builtin_amdgcn_s_barrier();

    for (int kt = 0; kt < NTK; ++kt) {
        const int cur = kt % 3;
        if (kt + 2 < NTK) STAGE((kt + 2) % 3, kt + 2);  // prefetch 2 ahead

        s16x8 aF[4], bF[4];
#pragma unroll
        for (int mt = 0; mt < 4; ++mt) {
            const int r = wr * 64 + mt * 16 + li;
            aF[mt] = *(const s16x8*)&lA[cur][r * 32 + ((g ^ ((r >> 1) & 3)) * 8)];
        }
#pragma unroll
        for (int nt = 0; nt < 4; ++nt) {
            const int r = wc * 64 + nt * 16 + li;
            bF[nt] = *(const s16x8*)&lB[cur][r * 32 + ((g ^ ((r >> 1) & 3)) * 8)];
        }
#pragma unroll
        for (int mt = 0; mt < 4; ++mt)
#pragma unroll
            for (int nt = 0; nt < 4; ++nt)
                acc[mt][nt] = __builtin_amdgcn_mfma_f32_16x16x32_bf16(
                    aF[mt], bF[nt], acc[mt][nt], 0, 0, 0);

        if (kt + 2 < NTK) {
            asm volatile("s_waitcnt vmcnt(4)" ::: "memory");
        } else {
            asm volatile("s_waitcnt vmcnt(0)" ::: "memory");
        }
        __builtin_amdgcn_s_barrier();
    }
#undef STAGE

    short* dstBF = (sel == 0) ? qws : kws;
#pragma unroll
    for (int nt = 0; nt < 4; ++nt) {
        const int col = bn + wc * 64 + nt * 16 + li;
        const float bcol = bias[col];
        const int h = col >> 6, d = col & 63;
#pragma unroll
        for (int mt = 0; mt < 4; ++mt) {
#pragma unroll
            for (int r = 0; r < 4; ++r) {
                const int row = bm + wr * 64 + mt * 16 + g * 4 + r;
                const int bb = row >> 10, n = row & 1023;
                const size_t off = ((size_t)(bb * Hc + h) * Nc + n) * Dc + d;
                dstBF[off] = f2bf(acc[mt][nt][r] + bcol);
            }
        }
    }
}

// ---------------------------------------------------------------------------
// Fused kernel: bid < 256 -> V-projection (fp32 reg-staged GEMM, writes out0)
//               bid >= 256 -> scores+softmax (round-10 structure, NT stores)
// The two block types have complementary profiles (MFMA/LDS vs HBM-write),
// so the hardware overlaps them; proj-V's serial ~15us hides under attn.
// proj-V reads ORIGINAL fp32 v/Wv (no scratch dependency -> no race with
// attn blocks overwriting the bf16 scratch region).
// ---------------------------------------------------------------------------
__global__ __launch_bounds__(512, 4)
void fused_kernel(const short* __restrict__ qws, const short* __restrict__ kws,
                  float* __restrict__ attnOut,
                  const float* __restrict__ vin, const float* __restrict__ Wv,
                  const float* __restrict__ bv, float* __restrict__ out0)
{
    __shared__ __align__(16) short lA[128 * 40];   // proj-V staging (padded)
    __shared__ __align__(16) short lB[128 * 40];
    __shared__ float red[8][32];                   // attn reduce

    const int bid = blockIdx.x;
    const int t   = threadIdx.x;
    const int lane = t & 63;

    if (bid < 256) {
        // ================= V-projection: 128x128 tile, 8 waves ==============
        const int bm = (bid & 31) * 128;
        const int bn = (bid >> 5) * 128;
        const int wid = t >> 6;
        const int wr = wid >> 2;              // 0..1: 64-row half
        const int wc = wid & 3;               // 0..3: 32-col quarter
        const int li = lane & 15, g = lane >> 4;

        const int srow = t >> 2;              // 0..127
        const int scol = (t & 3) * 8;         // 8 floats

        const float* Xs = vin + (size_t)(bm + srow) * Ec + scol;
        const float* Ws = Wv  + (size_t)(bn + srow) * Ec + scol;

        f32x4 a0 = *(const f32x4*)(Xs);
        f32x4 a1 = *(const f32x4*)(Xs + 4);
        f32x4 b0 = *(const f32x4*)(Ws);
        f32x4 b1 = *(const f32x4*)(Ws + 4);

        f32x4 acc[4][2];
#pragma unroll
        for (int i = 0; i < 4; ++i)
#pragma unroll
            for (int j = 0; j < 2; ++j)
                acc[i][j] = (f32x4){0.f, 0.f, 0.f, 0.f};

        for (int kt = 0; kt < 32; ++kt) {
            // write staged regs (converted) to LDS
            {
                s16x8 ha, hb;
#pragma unroll
                for (int i = 0; i < 4; ++i) {
                    ha[i] = f2bf(a0[i]); ha[i + 4] = f2bf(a1[i]);
                    hb[i] = f2bf(b0[i]); hb[i + 4] = f2bf(b1[i]);
                }
                *(s16x8*)&lA[srow * 40 + scol] = ha;
                *(s16x8*)&lB[srow * 40 + scol] = hb;
            }
            __syncthreads();

            // prefetch next tile
            if (kt < 31) {
                const int kb = (kt + 1) * 32;
                a0 = *(const f32x4*)(Xs + kb);
                a1 = *(const f32x4*)(Xs + kb + 4);
                b0 = *(const f32x4*)(Ws + kb);
                b1 = *(const f32x4*)(Ws + kb + 4);
            }

            s16x8 aF[4], bF[2];
#pragma unroll
            for (int mt = 0; mt < 4; ++mt)
                aF[mt] = *(const s16x8*)&lA[(wr * 64 + mt * 16 + li) * 40 + g * 8];
#pragma unroll
            for (int nt = 0; nt < 2; ++nt)
                bF[nt] = *(const s16x8*)&lB[(wc * 32 + nt * 16 + li) * 40 + g * 8];
#pragma unroll
            for (int mt = 0; mt < 4; ++mt)
#pragma unroll
                for (int nt = 0; nt < 2; ++nt)
                    acc[mt][nt] = __builtin_amdgcn_mfma_f32_16x16x32_bf16(
                        aF[mt], bF[nt], acc[mt][nt], 0, 0, 0);
            __syncthreads();
        }

        // epilogue: bias + head-split scatter (fp32 to out0)
#pragma unroll
        for (int nt = 0; nt < 2; ++nt) {
            const int col = bn + wc * 32 + nt * 16 + li;
            const float bcol = bv[col];
            const int h = col >> 6, d = col & 63;
#pragma unroll
            for (int mt = 0; mt < 4; ++mt) {
#pragma unroll
                for (int r = 0; r < 4; ++r) {
                    const int row = bm + wr * 64 + mt * 16 + g * 4 + r;
                    const int bb = row >> 10, n = row & 1023;
                    out0[((size_t)(bb * Hc + h) * Nc + n) * Dc + d] =
                        acc[mt][nt][r] + bcol;
                }
            }
        }
        return;
    }

    // ===================== attn: scores + softmax =========================
    const int abid = bid - 256;                 // 0..2047
    const int rb  = (abid >> 3) & 31;           // 32-row block
    const int bh  = ((abid & 7) << 3) | (abid >> 8);  // head: abid%8 == bh>>3
    const int w  = t >> 6;                      // 0..7
    const int li = lane & 31;
    const int hi = lane >> 5;

    const short* Qb = qws + (size_t)bh * (Nc * Dc);
    const short* Kb = kws + (size_t)bh * (Nc * Dc);

    s16x8 qF[4];
    {
        const short* qp = Qb + (size_t)(rb * 32 + li) * Dc + hi * 8;
#pragma unroll
        for (int s = 0; s < 4; ++s)
            qF[s] = *(const s16x8*)(qp + s * 16);
    }

    f32x16 acc[4];
#pragma unroll
    for (int i = 0; i < 4; ++i) acc[i] = (f32x16)(0.f);

    const int colbase = w * 128;                // wave owns 128 cols
#pragma unroll
    for (int ct = 0; ct < 4; ++ct) {
        const short* kp = Kb + (size_t)(colbase + ct * 32 + li) * Dc + hi * 8;
#pragma unroll
        for (int s = 0; s < 4; ++s) {
            s16x8 kf = *(const s16x8*)(kp + s * 16);
            acc[ct] = __builtin_amdgcn_mfma_f32_32x32x16_bf16(qF[s], kf, acc[ct], 0, 0, 0);
        }
    }

    // exp + row partial sum (no max subtraction; scores tiny in exp2 space)
    const float c = 1.44269504f / 32.0f;   // log2(e)/SCALE, SCALE = 32
    float sm[16];
#pragma unroll
    for (int r = 0; r < 16; ++r) sm[r] = 0.f;
#pragma unroll
    for (int ct = 0; ct < 4; ++ct) {
#pragma unroll
        for (int r = 0; r < 16; ++r) {
            float p = __builtin_amdgcn_exp2f(acc[ct][r] * c);
            acc[ct][r] = p;
            sm[r] += p;
        }
    }
#pragma unroll
    for (int r = 0; r < 16; ++r) {
#pragma unroll
        for (int off = 1; off < 32; off <<= 1)
            sm[r] += __shfl_xor(sm[r], off);
    }

    if (li == 0) {
#pragma unroll
        for (int r = 0; r < 16; ++r)
            red[w][(r & 3) + 8 * (r >> 2) + 4 * hi] = sm[r];
    }
    __syncthreads();
#pragma unroll
    for (int r = 0; r < 16; ++r) {
        const int row = (r & 3) + 8 * (r >> 2) + 4 * hi;
        float s = red[0][row] + red[1][row] + red[2][row] + red[3][row] +
                  red[4][row] + red[5][row] + red[6][row] + red[7][row];
        sm[r] = 1.0f / s;
    }

    // NT stores: full 128B-line segments (R11 A/B: NT beats cached by ~8us)
    float* outp = attnOut + (size_t)bh * (Nc * Nc) + (size_t)(rb * 32) * Nc;
#pragma unroll
    for (int ct = 0; ct < 4; ++ct) {
        const int col = colbase + ct * 32 + li;
#pragma unroll
        for (int r = 0; r < 16; ++r) {
            const int row = (r & 3) + 8 * (r >> 2) + 4 * hi;
            __builtin_nontemporal_store(acc[ct][r] * sm[r],
                                        &outp[(size_t)row * Nc + col]);
        }
    }
}

extern "C" void kernel_launch(void* const* d_in, const int* in_sizes, int n_in,
                              void* d_out, int out_size, void* d_ws, size_t ws_size,
                              hipStream_t stream) {
    const float* q  = (const float*)d_in[0];
    const float* k  = (const float*)d_in[1];
    const float* v  = (const float*)d_in[2];
    const float* Wq = (const float*)d_in[3];
    const float* bq = (const float*)d_in[4];
    const float* Wk = (const float*)d_in[5];
    const float* bk = (const float*)d_in[6];
    const float* Wv = (const float*)d_in[7];
    const float* bv = (const float*)d_in[8];

    float* out0 = (float*)d_out;                      // (B,H,N,D) fp32
    float* attn = (float*)d_out + OUT0_ELEMS;         // (B,H,N,N) fp32

    // bf16 scratch in the TAIL of the attn region (20 MB). Read only by
    // proj_kernel, which completes before the fused kernel starts; the
    // fused kernel's attn blocks may then freely overwrite it.
    short* s16  = (short*)(attn + SCRATCH_OFF);
    short* xall = s16;                                // Xq|Xk bf16
    short* wall = s16 + 8388608;                      // Wq|Wk bf16

    short* qws = (short*)d_ws;                        // bf16 Q [b][h][n][d]
    short* kws = qws + (size_t)Mc * Ec;               // bf16 K [b][h][n][d]

    cvt_kernel<<<dim3(2048, 4), 256, 0, stream>>>(q, k, Wq, Wk, s16);
    proj_kernel<<<dim3(32, 8, 2), 256, 0, stream>>>(
        xall, wall, bq, bk, qws, kws);
    fused_kernel<<<2304, 512, 0, stream>>>(qws, kws, attn, v, Wv, bv, out0);
}